// Round 2
// baseline (80.336 us; speedup 1.0000x reference)
//
#include <hip/hip_runtime.h>

// STFT -> mag/phase recombine -> iSTFT with pinv basis is a mathematically
// exact identity:
//   * mag*cos(atan2(im,re)) == re, mag*sin(...) == im  (recombine == fwd)
//   * ib = pinv(scale*A).T applied against fb collapses: sum_c fb[c,n]*ib[c,j]
//     = win[n]*win[j]*(hop/N)*delta_{nj}   (A has full column rank 1024)
//   * overlap-add gives out[l] = xp[l] * wsum[l] * (hop/N); reference divides
//     by wsum and multiplies by N/hop -> xp[l]; slice [512:-512] == input.
// So the reference output equals input_data up to f32 conv rounding noise.
// Roofline-minimal implementation: vectorized device copy (64 MiB traffic).

__global__ void identity_copy_f4(const float4* __restrict__ in,
                                 float4* __restrict__ out, int n4) {
    int i = blockIdx.x * blockDim.x + threadIdx.x;
    const int stride = gridDim.x * blockDim.x;
    for (; i < n4; i += stride) {
        out[i] = in[i];
    }
}

extern "C" void kernel_launch(void* const* d_in, const int* in_sizes, int n_in,
                              void* d_out, int out_size, void* d_ws, size_t ws_size,
                              hipStream_t stream) {
    const float* x = (const float*)d_in[0];
    float* out = (float*)d_out;
    const int n = in_sizes[0];          // 32 * 262144 = 8388608 floats
    const int n4 = n >> 2;              // exactly divisible (2^23 / 4)

    const int block = 256;
    const int grid = 2048;              // 256 CUs x 8 blocks, grid-stride

    identity_copy_f4<<<grid, block, 0, stream>>>(
        (const float4*)x, (float4*)out, n4);
}

// Round 7
// 79.071 us; speedup vs baseline: 1.0160x; 1.0160x over previous
//
#include <hip/hip_runtime.h>

// STFT -> mag/phase recombine -> iSTFT with pinv basis is a mathematically
// exact identity (verified on HW round 2: absmax=0.0156 = the reference's own
// f32 conv rounding noise, passed):
//   * mag*cos(atan2(im,re)) == re, mag*sin(...) == im  (recombine == fwd)
//   * sum_c fb[c,n]*ib[c,j] = win[j]^2*(hop/N)*delta_{nj}  (full-col-rank DFT)
//   * overlap-add * (N/hop) / wsum == xp; slice [512:-512] == input.
// Roofline-minimal realization: 33.5 MB read + 33.5 MB write.
// Rounds 3-7 A/B: runtime D2D copy (hipMemcpyAsync is graph-capture-safe per
// harness contract) vs. round 2's hand-rolled float4 kernel (dur_us=80.3,
// but kernel absent from top-5 profile => device time < 42.6us; isolating
// whether 80us is kernel time or graph-replay/harness floor).
// Rounds 3-6 all failed on GPUAcquisitionTimeout (broker at capacity) --
// no device evidence since round 2; resubmitting unchanged.

extern "C" void kernel_launch(void* const* d_in, const int* in_sizes, int n_in,
                              void* d_out, int out_size, void* d_ws, size_t ws_size,
                              hipStream_t stream) {
    const size_t bytes = (size_t)in_sizes[0] * sizeof(float);  // 33.5 MB
    hipMemcpyAsync(d_out, d_in[0], bytes, hipMemcpyDeviceToDevice, stream);
}